// Round 11
// baseline (300.741 us; speedup 1.0000x reference)
//
#include <hip/hip_runtime.h>
#include <hip/hip_fp16.h>

#define NN 131072
#define EE 524288
#define BCAP 4608u   // fixed per-bucket region capacity (mean 4096, +8 sigma)

typedef _Float16 f16x8 __attribute__((ext_vector_type(8)));
typedef float f32x4 __attribute__((ext_vector_type(4)));

__device__ __forceinline__ unsigned short f2h(float f) {
  __half h = __float2half(f);
  unsigned short r;
  __builtin_memcpy(&r, &h, 2);
  return r;
}
__device__ __forceinline__ __half2 u2h2(unsigned u) {
  __half2 h;
  __builtin_memcpy(&h, &u, 4);
  return h;
}
__device__ __forceinline__ unsigned h22u(__half2 h) {
  unsigned u;
  __builtin_memcpy(&u, &h, 4);
  return u;
}

// ---------------- fused prep: cast X, build W image, cursor init, bias sums ----------------
// blocks [0,16384): kcast; [16384,16896): kwconv3; 16896-16897: cursor init; 16898: bias
__global__ __launch_bounds__(256) void kprep(
    const float4* __restrict__ x, ushort4* __restrict__ xo,
    const float* __restrict__ m0, const float* __restrict__ m1, const float* __restrict__ m2, const float* __restrict__ m3,
    const float* __restrict__ m4, const float* __restrict__ m5, const float* __restrict__ m6, const float* __restrict__ m7,
    unsigned short* __restrict__ img,
    unsigned* __restrict__ cursor,
    const float* __restrict__ a0, const float* __restrict__ a1, const float* __restrict__ a2, const float* __restrict__ a3,
    const float* __restrict__ c0, const float* __restrict__ c1, const float* __restrict__ c2, const float* __restrict__ c3,
    float* __restrict__ bsum) {
  unsigned b = blockIdx.x;
  int tid = threadIdx.x;
  if (b < 16384u) {                       // X cast: fp32 -> fp16
    unsigned i = b * 256u + tid;
    float4 v = x[i];
    ushort4 r;
    r.x = f2h(v.x); r.y = f2h(v.y); r.z = f2h(v.z); r.w = f2h(v.w);
    xo[i] = r;
  } else if (b < 16896u) {                // W -> fragment-ordered fp16 image
    unsigned gidx = (b - 16384u) * 256u + tid;   // 0..131071
    unsigned L = gidx >> 16;
    unsigned r = gidx & 65535u;
    unsigned kc = r >> 12;
    unsigned khi = (r >> 10) & 3u;
    unsigned cc = (r >> 3) & 127u;
    unsigned j = r & 7u;
    unsigned k = kc * 32u + khi * 8u + j;
    unsigned t = k >> 7, krow = k & 127u;
    const float* W;
    if (L == 0) W = (t == 0) ? m0 : (t == 1) ? m1 : (t == 2) ? m2 : m3;
    else        W = (t == 0) ? m4 : (t == 1) ? m5 : (t == 2) ? m6 : m7;
    img[gidx] = f2h(W[krow * 128 + cc]);
  } else if (b < 16898u) {                // cursor init
    unsigned i = (b - 16896u) * 256u + tid;
    cursor[i] = i * BCAP;
  } else {                                // bias sums
    if (tid < 128) bsum[tid] = a0[tid] + a1[tid] + a2[tid] + a3[tid];
    else { int c = tid - 128; bsum[128 + c] = c0[c] + c1[c] + c2[c] + c3[c]; }
  }
}

// ---------------- phase A: bin edges into 512 fixed coarse-bucket regions ----------------
// record: word0 = src | (lowkey<<17), word1 = bits(w); lowkey = (dst&255)*4 + t
__global__ __launch_bounds__(256) void kbinA(
    const int* __restrict__ e0, const int* __restrict__ e1, const int* __restrict__ e2, const int* __restrict__ e3,
    const float* __restrict__ w0, const float* __restrict__ w1, const float* __restrict__ w2, const float* __restrict__ w3,
    unsigned* __restrict__ cursor, uint2* __restrict__ tmp) {
  __shared__ unsigned hist[512];
  __shared__ unsigned base[512];
  int tid = threadIdx.x;
  unsigned t = blockIdx.x >> 7;
  unsigned chunk = blockIdx.x & 127u;
  const int* ei = (t == 0) ? e0 : (t == 1) ? e1 : (t == 2) ? e2 : e3;
  const float* ew = (t == 0) ? w0 : (t == 1) ? w1 : (t == 2) ? w2 : w3;
  const uint4* src4 = (const uint4*)ei;
  const uint4* dst4 = (const uint4*)(ei + EE);
  const float4* w4 = (const float4*)ew;
  unsigned ib4 = chunk * 1024u;           // quad index base (4096 edges / 4)
  for (int i = tid; i < 512; i += 256) hist[i] = 0;
  __syncthreads();
  unsigned km[16], sm[16];
  float wm[16];
#pragma unroll
  for (int k = 0; k < 4; ++k) {
    unsigned i4 = ib4 + k * 256u + tid;
    uint4 s = src4[i4];
    uint4 d = dst4[i4];
    float4 w = w4[i4];
    sm[k * 4 + 0] = s.x; sm[k * 4 + 1] = s.y; sm[k * 4 + 2] = s.z; sm[k * 4 + 3] = s.w;
    wm[k * 4 + 0] = w.x; wm[k * 4 + 1] = w.y; wm[k * 4 + 2] = w.z; wm[k * 4 + 3] = w.w;
    km[k * 4 + 0] = (d.x << 2) | t; km[k * 4 + 1] = (d.y << 2) | t;
    km[k * 4 + 2] = (d.z << 2) | t; km[k * 4 + 3] = (d.w << 2) | t;
    atomicAdd(&hist[d.x >> 8], 1u);
    atomicAdd(&hist[d.y >> 8], 1u);
    atomicAdd(&hist[d.z >> 8], 1u);
    atomicAdd(&hist[d.w >> 8], 1u);
  }
  __syncthreads();
  for (int j = tid; j < 512; j += 256) {
    unsigned c = hist[j];
    base[j] = c ? atomicAdd(&cursor[j], c) : 0u;
    hist[j] = 0u;                        // reuse as local cursor
  }
  __syncthreads();
#pragma unroll
  for (int k = 0; k < 16; ++k) {
    unsigned b = km[k] >> 10;
    unsigned l = atomicAdd(&hist[b], 1u);
    unsigned pos = base[b] + l;
    if (pos < (b + 1u) * BCAP)           // overflow guard (unreachable at +8 sigma)
      tmp[(size_t)pos] = make_uint2(sm[k] | ((km[k] & 1023u) << 17), __float_as_uint(wm[k]));
  }
}

// ---------------- phase B: per-bucket counting sort over 1024 fine keys ----------------
// rp_fine stride 1025/bucket; entry 1024 = bucket end sentinel.
__global__ __launch_bounds__(256) void kbinB(const unsigned* __restrict__ cursor, const uint2* __restrict__ tmp,
                                             unsigned* __restrict__ rp_fine, uint2* __restrict__ edges) {
  __shared__ unsigned cnts[1024];
  __shared__ unsigned ps[256];
  int tid = threadIdx.x;
  unsigned b = blockIdx.x;
  unsigned s = b * BCAP;
  unsigned cnt = min(cursor[b], (b + 1u) * BCAP) - s;
  for (int j = tid; j < 1024; j += 256) cnts[j] = 0;
  __syncthreads();
  for (unsigned i = tid; i < cnt; i += 256) {
    unsigned lk = tmp[s + i].x >> 17;
    atomicAdd(&cnts[lk], 1u);
  }
  __syncthreads();
  unsigned c4[4], lsum = 0;
#pragma unroll
  for (int q = 0; q < 4; ++q) { c4[q] = cnts[tid * 4 + q]; lsum += c4[q]; }
  ps[tid] = lsum;
  __syncthreads();
  for (int o = 1; o < 256; o <<= 1) {
    unsigned v = (tid >= o) ? ps[tid - o] : 0u;
    __syncthreads();
    ps[tid] += v;
    __syncthreads();
  }
  unsigned excl = ps[tid] - lsum;
  __syncthreads();
#pragma unroll
  for (int q = 0; q < 4; ++q) {
    rp_fine[b * 1025u + (unsigned)tid * 4u + q] = s + excl;
    cnts[tid * 4 + q] = excl;            // lcur init
    excl += c4[q];
  }
  if (tid == 255) rp_fine[b * 1025u + 1024u] = s + cnt;
  __syncthreads();
  for (unsigned i = tid; i < cnt; i += 256) {
    uint2 r = tmp[s + i];
    unsigned lk = r.x >> 17;
    unsigned p = atomicAdd(&cnts[lk], 1u);
    edges[(size_t)s + p] = make_uint2(r.x & 0x1ffffu, r.y);
  }
}

// ---------------- FUSED: gather -> LDS(64KB) -> MFMA (B from L2) -> bias+LN -> out ----------------
// 1024 threads (16 waves), 64 dsts/block; 2 blocks/CU -> 32 waves/CU (100% occ).
__global__ __launch_bounds__(1024, 8) void kfuse(const uint2* __restrict__ edges, const unsigned* __restrict__ rp,
                                                 const unsigned short* __restrict__ X,
                                                 const unsigned short* __restrict__ Wimg, int layer,
                                                 const float* __restrict__ bsum,
                                                 const float* __restrict__ gw, const float* __restrict__ bw,
                                                 unsigned short* __restrict__ outh, float* __restrict__ outf, int wf32) {
  __shared__ unsigned short sZ[64 * 512];   // 64KB
  const int tid = threadIdx.x;
  const int wv = tid >> 6;                  // 0..15
  const int lane = tid & 63;
  const int g = lane >> 4;
  const int cl = lane & 15;
  const unsigned dbase = blockIdx.x * 64u;

  // ---- gather phase: each wave fills 4 rows of sZ ----
  const unsigned short* Xr = X + (size_t)(cl * 8);
  for (int it = 0; it < 4; ++it) {
    unsigned row = (unsigned)(wv * 4 + it);
    unsigned d = dbase + row;
    unsigned ridx = (d >> 8) * 1025u + ((d & 255u) << 2) + (unsigned)g;
    unsigned s = rp[ridx];
    unsigned e = rp[ridx + 1];
    unsigned len = e - s;
    int m = (int)len;
    m = max(m, __shfl_xor(m, 16, 64));
    m = max(m, __shfl_xor(m, 32, 64));
    __half2 accA[4], accB[4];
    const __half2 z2 = __half2(__half(0.f), __half(0.f));
#pragma unroll
    for (int k = 0; k < 4; ++k) { accA[k] = z2; accB[k] = z2; }
    unsigned jlast = len ? e - 1u : s;
    for (int i = 0; i < m; i += 4) {
      unsigned j[4], sidx[4];
      uint2 q[4];
      __half2 w2[4];
#pragma unroll
      for (int k = 0; k < 4; ++k) {
        bool v = (unsigned)(i + k) < len;
        j[k] = v ? s + (unsigned)(i + k) : jlast;
      }
#pragma unroll
      for (int k = 0; k < 4; ++k) q[k] = edges[j[k]];
#pragma unroll
      for (int k = 0; k < 4; ++k) {
        bool v = (unsigned)(i + k) < len;
        sidx[k] = v ? q[k].x : 0u;
        w2[k] = __float2half2_rn(v ? __uint_as_float(q[k].y) : 0.f);
      }
      uint4 u0 = *(const uint4*)(Xr + (size_t)sidx[0] * 128);
      uint4 u1 = *(const uint4*)(Xr + (size_t)sidx[1] * 128);
      uint4 u2 = *(const uint4*)(Xr + (size_t)sidx[2] * 128);
      uint4 u3 = *(const uint4*)(Xr + (size_t)sidx[3] * 128);
      accA[0] = __hfma2(w2[0], u2h2(u0.x), accA[0]);
      accA[1] = __hfma2(w2[0], u2h2(u0.y), accA[1]);
      accA[2] = __hfma2(w2[0], u2h2(u0.z), accA[2]);
      accA[3] = __hfma2(w2[0], u2h2(u0.w), accA[3]);
      accB[0] = __hfma2(w2[1], u2h2(u1.x), accB[0]);
      accB[1] = __hfma2(w2[1], u2h2(u1.y), accB[1]);
      accB[2] = __hfma2(w2[1], u2h2(u1.z), accB[2]);
      accB[3] = __hfma2(w2[1], u2h2(u1.w), accB[3]);
      accA[0] = __hfma2(w2[2], u2h2(u2.x), accA[0]);
      accA[1] = __hfma2(w2[2], u2h2(u2.y), accA[1]);
      accA[2] = __hfma2(w2[2], u2h2(u2.z), accA[2]);
      accA[3] = __hfma2(w2[2], u2h2(u2.w), accA[3]);
      accB[0] = __hfma2(w2[3], u2h2(u3.x), accB[0]);
      accB[1] = __hfma2(w2[3], u2h2(u3.y), accB[1]);
      accB[2] = __hfma2(w2[3], u2h2(u3.z), accB[2]);
      accB[3] = __hfma2(w2[3], u2h2(u3.w), accB[3]);
    }
    uint4 o;
    o.x = h22u(__hadd2(accA[0], accB[0]));
    o.y = h22u(__hadd2(accA[1], accB[1]));
    o.z = h22u(__hadd2(accA[2], accB[2]));
    o.w = h22u(__hadd2(accA[3], accB[3]));
    *(uint4*)((char*)sZ + row * 1024 + (((unsigned)(g * 256 + cl * 16)) ^ ((row & 7u) << 4))) = o;
  }
  __syncthreads();

  // ---- MFMA phase: [64x512] x [512x128]; wave=(mt,nh): 16 rows x 32 cols ----
  const int rlo = lane & 15;
  const int khi = lane >> 4;
  const int mt = wv >> 2;                 // 0..3
  const int nh = wv & 3;
  f32x4 acc[2];
  acc[0] = (f32x4){0.f, 0.f, 0.f, 0.f};
  acc[1] = (f32x4){0.f, 0.f, 0.f, 0.f};
  const unsigned short* WL = Wimg + (size_t)layer * 65536;
  const int arow = mt * 16 + rlo;
  const unsigned abase = (unsigned)(arow * 1024);
  const unsigned aswz = (unsigned)((arow & 7) << 4);
#pragma unroll 4
  for (int kc = 0; kc < 16; ++kc) {
    f16x8 a = *(const f16x8*)((const char*)sZ + abase + (((unsigned)(kc * 64 + khi * 16)) ^ aswz));
    const f16x8* bp = (const f16x8*)(WL + (size_t)(((kc * 4 + khi) * 128) + nh * 32 + rlo) * 8);
    acc[0] = __builtin_amdgcn_mfma_f32_16x16x32_f16(a, bp[0], acc[0], 0, 0, 0);
    acc[1] = __builtin_amdgcn_mfma_f32_16x16x32_f16(a, bp[16], acc[1], 0, 0, 0);
  }

  // ---- epilogue: bias + LN; cross-wave column partials via LDS (reuse sZ) ----
  float bs[2], ggv[2], bwv[2];
#pragma unroll
  for (int n = 0; n < 2; ++n) {
    int cc = nh * 32 + n * 16 + rlo;
    bs[n] = bsum[cc];
    ggv[n] = gw[cc];
    bwv[n] = bw[cc];
  }
  __syncthreads();             // all MFMA reads of sZ done
  float* sPart = (float*)sZ;   // [64 rows][4 nh][2]
#pragma unroll
  for (int rg = 0; rg < 4; ++rg) {
    float v0 = acc[0][rg] + bs[0];
    float v1 = acc[1][rg] + bs[1];
    float s1 = v0 + v1;
    float s2 = v0 * v0 + v1 * v1;
    s1 += __shfl_xor(s1, 1, 64); s2 += __shfl_xor(s2, 1, 64);
    s1 += __shfl_xor(s1, 2, 64); s2 += __shfl_xor(s2, 2, 64);
    s1 += __shfl_xor(s1, 4, 64); s2 += __shfl_xor(s2, 4, 64);
    s1 += __shfl_xor(s1, 8, 64); s2 += __shfl_xor(s2, 8, 64);
    if (rlo == 0) {
      int row = mt * 16 + khi * 4 + rg;
      sPart[row * 8 + nh * 2] = s1;
      sPart[row * 8 + nh * 2 + 1] = s2;
    }
  }
  __syncthreads();
#pragma unroll
  for (int rg = 0; rg < 4; ++rg) {
    int row = mt * 16 + khi * 4 + rg;
    float s1 = sPart[row * 8 + 0] + sPart[row * 8 + 2] + sPart[row * 8 + 4] + sPart[row * 8 + 6];
    float s2 = sPart[row * 8 + 1] + sPart[row * 8 + 3] + sPart[row * 8 + 5] + sPart[row * 8 + 7];
    float mu = s1 * (1.f / 128.f);
    float var = fmaxf(s2 * (1.f / 128.f) - mu * mu, 0.f);
    float inv = rsqrtf(var + 1e-5f);
    size_t d = (size_t)dbase + (unsigned)row;
    if (wf32) {
#pragma unroll
      for (int n = 0; n < 2; ++n) {
        int cc = nh * 32 + n * 16 + rlo;
        outf[d * 128 + cc] = (acc[n][rg] + bs[n] - mu) * inv * ggv[n] + bwv[n];
      }
    } else {
#pragma unroll
      for (int n = 0; n < 2; ++n) {
        int cc = nh * 32 + n * 16 + rlo;
        outh[d * 128 + cc] = f2h((acc[n][rg] + bs[n] - mu) * inv * ggv[n] + bwv[n]);
      }
    }
  }
}

extern "C" void kernel_launch(void* const* d_in, const int* in_sizes, int n_in,
                              void* d_out, int out_size, void* d_ws, size_t ws_size,
                              hipStream_t stream) {
  (void)n_in; (void)out_size; (void)ws_size;
  const float* x = (const float*)d_in[0];
  const int* ei[4];
  const float *ew[4], *W1[4], *b1[4], *W2[4], *b2[4];
  const float *g1, *be1, *g2, *be2;
  if (in_sizes[2] == EE) {  // setup_inputs dict order
    for (int t = 0; t < 4; ++t) {
      int base = 1 + t * 6;
      ei[t] = (const int*)d_in[base + 0];
      ew[t] = (const float*)d_in[base + 1];
      W1[t] = (const float*)d_in[base + 2];
      b1[t] = (const float*)d_in[base + 3];
      W2[t] = (const float*)d_in[base + 4];
      b2[t] = (const float*)d_in[base + 5];
    }
  } else {  // reference() argument order
    for (int t = 0; t < 4; ++t) {
      ei[t] = (const int*)d_in[1 + t];
      ew[t] = (const float*)d_in[5 + t];
      W1[t] = (const float*)d_in[9 + t * 4 + 0];
      b1[t] = (const float*)d_in[9 + t * 4 + 1];
      W2[t] = (const float*)d_in[9 + t * 4 + 2];
      b2[t] = (const float*)d_in[9 + t * 4 + 3];
    }
  }
  g1 = (const float*)d_in[25];
  be1 = (const float*)d_in[26];
  g2 = (const float*)d_in[27];
  be2 = (const float*)d_in[28];

  char* ws = (char*)d_ws;
  size_t off = 0;
  auto take = [&](size_t b) { char* p = ws + off; off = (off + b + 255) & ~(size_t)255; return p; };
  unsigned* cursor  = (unsigned*)take(512 * 4);
  unsigned* rp_fine = (unsigned*)take(512ull * 1025 * 4);
  unsigned short* Wimg3 = (unsigned short*)take(2ull * 65536 * 2);
  float* bsum       = (float*)take(256 * 4);
  uint2* edges      = (uint2*)take(512ull * BCAP * 8);
  unsigned short* Xh = (unsigned short*)take((size_t)NN * 128 * 2);
  unsigned short* Yh = (unsigned short*)take((size_t)NN * 128 * 2);
  uint2* tmp = (uint2*)d_out;  // 18.9 MB scratch; dead before any d_out output write

  kprep<<<16899, 256, 0, stream>>>((const float4*)x, (ushort4*)Xh,
                                   W1[0], W1[1], W1[2], W1[3], W2[0], W2[1], W2[2], W2[3], Wimg3,
                                   cursor,
                                   b1[0], b1[1], b1[2], b1[3], b2[0], b2[1], b2[2], b2[3], bsum);
  kbinA<<<512, 256, 0, stream>>>(ei[0], ei[1], ei[2], ei[3], ew[0], ew[1], ew[2], ew[3], cursor, tmp);
  kbinB<<<512, 256, 0, stream>>>(cursor, tmp, rp_fine, edges);

  // layer 1: fused gather+GEMM+LN -> Yh (fp16, workspace)
  kfuse<<<NN / 64, 1024, 0, stream>>>(edges, rp_fine, Xh, Wimg3, 0, bsum, g1, be1, Yh, nullptr, 0);
  // layer 2: fused gather+GEMM+LN -> d_out (fp32)
  kfuse<<<NN / 64, 1024, 0, stream>>>(edges, rp_fine, Yh, Wimg3, 1, bsum + 128, g2, be2, nullptr, (float*)d_out, 1);
}

// Round 12
// 281.011 us; speedup vs baseline: 1.0702x; 1.0702x over previous
//
#include <hip/hip_runtime.h>
#include <hip/hip_fp16.h>

#define NN 131072
#define EE 524288
#define BCAP 4608u   // fixed per-bucket region capacity (mean 4096, +8 sigma)

typedef _Float16 f16x8 __attribute__((ext_vector_type(8)));
typedef float f32x4 __attribute__((ext_vector_type(4)));

__device__ __forceinline__ unsigned short f2h(float f) {
  __half h = __float2half(f);
  unsigned short r;
  __builtin_memcpy(&r, &h, 2);
  return r;
}
__device__ __forceinline__ __half2 u2h2(unsigned u) {
  __half2 h;
  __builtin_memcpy(&h, &u, 4);
  return h;
}
__device__ __forceinline__ unsigned h22u(__half2 h) {
  unsigned u;
  __builtin_memcpy(&u, &h, 4);
  return u;
}

// ---------------- fused prep: cast X, build W image, cursor init, bias sums ----------------
// blocks [0,16384): kcast; [16384,16896): kwconv3; 16896-16897: cursor init; 16898: bias
__global__ __launch_bounds__(256) void kprep(
    const float4* __restrict__ x, ushort4* __restrict__ xo,
    const float* __restrict__ m0, const float* __restrict__ m1, const float* __restrict__ m2, const float* __restrict__ m3,
    const float* __restrict__ m4, const float* __restrict__ m5, const float* __restrict__ m6, const float* __restrict__ m7,
    unsigned short* __restrict__ img,
    unsigned* __restrict__ cursor,
    const float* __restrict__ a0, const float* __restrict__ a1, const float* __restrict__ a2, const float* __restrict__ a3,
    const float* __restrict__ c0, const float* __restrict__ c1, const float* __restrict__ c2, const float* __restrict__ c3,
    float* __restrict__ bsum) {
  unsigned b = blockIdx.x;
  int tid = threadIdx.x;
  if (b < 16384u) {                       // X cast: fp32 -> fp16
    unsigned i = b * 256u + tid;
    float4 v = x[i];
    ushort4 r;
    r.x = f2h(v.x); r.y = f2h(v.y); r.z = f2h(v.z); r.w = f2h(v.w);
    xo[i] = r;
  } else if (b < 16896u) {                // W -> fragment-ordered fp16 image
    unsigned gidx = (b - 16384u) * 256u + tid;   // 0..131071
    unsigned L = gidx >> 16;
    unsigned r = gidx & 65535u;
    unsigned kc = r >> 12;
    unsigned khi = (r >> 10) & 3u;
    unsigned cc = (r >> 3) & 127u;
    unsigned j = r & 7u;
    unsigned k = kc * 32u + khi * 8u + j;
    unsigned t = k >> 7, krow = k & 127u;
    const float* W;
    if (L == 0) W = (t == 0) ? m0 : (t == 1) ? m1 : (t == 2) ? m2 : m3;
    else        W = (t == 0) ? m4 : (t == 1) ? m5 : (t == 2) ? m6 : m7;
    img[gidx] = f2h(W[krow * 128 + cc]);
  } else if (b < 16898u) {                // cursor init
    unsigned i = (b - 16896u) * 256u + tid;
    cursor[i] = i * BCAP;
  } else {                                // bias sums
    if (tid < 128) bsum[tid] = a0[tid] + a1[tid] + a2[tid] + a3[tid];
    else { int c = tid - 128; bsum[128 + c] = c0[c] + c1[c] + c2[c] + c3[c]; }
  }
}

// ---------------- phase A: bin edges into 512 fixed coarse-bucket regions ----------------
// record: word0 = src | (lowkey<<17), word1 = bits(w); lowkey = (dst&255)*4 + t
__global__ __launch_bounds__(256) void kbinA(
    const int* __restrict__ e0, const int* __restrict__ e1, const int* __restrict__ e2, const int* __restrict__ e3,
    const float* __restrict__ w0, const float* __restrict__ w1, const float* __restrict__ w2, const float* __restrict__ w3,
    unsigned* __restrict__ cursor, uint2* __restrict__ tmp) {
  __shared__ unsigned hist[512];
  __shared__ unsigned base[512];
  int tid = threadIdx.x;
  unsigned t = blockIdx.x >> 7;
  unsigned chunk = blockIdx.x & 127u;
  const int* ei = (t == 0) ? e0 : (t == 1) ? e1 : (t == 2) ? e2 : e3;
  const float* ew = (t == 0) ? w0 : (t == 1) ? w1 : (t == 2) ? w2 : w3;
  const uint4* src4 = (const uint4*)ei;
  const uint4* dst4 = (const uint4*)(ei + EE);
  const float4* w4 = (const float4*)ew;
  unsigned ib4 = chunk * 1024u;           // quad index base (4096 edges / 4)
  for (int i = tid; i < 512; i += 256) hist[i] = 0;
  __syncthreads();
  unsigned km[16], sm[16];
  float wm[16];
#pragma unroll
  for (int k = 0; k < 4; ++k) {
    unsigned i4 = ib4 + k * 256u + tid;
    uint4 s = src4[i4];
    uint4 d = dst4[i4];
    float4 w = w4[i4];
    sm[k * 4 + 0] = s.x; sm[k * 4 + 1] = s.y; sm[k * 4 + 2] = s.z; sm[k * 4 + 3] = s.w;
    wm[k * 4 + 0] = w.x; wm[k * 4 + 1] = w.y; wm[k * 4 + 2] = w.z; wm[k * 4 + 3] = w.w;
    km[k * 4 + 0] = (d.x << 2) | t; km[k * 4 + 1] = (d.y << 2) | t;
    km[k * 4 + 2] = (d.z << 2) | t; km[k * 4 + 3] = (d.w << 2) | t;
    atomicAdd(&hist[d.x >> 8], 1u);
    atomicAdd(&hist[d.y >> 8], 1u);
    atomicAdd(&hist[d.z >> 8], 1u);
    atomicAdd(&hist[d.w >> 8], 1u);
  }
  __syncthreads();
  for (int j = tid; j < 512; j += 256) {
    unsigned c = hist[j];
    base[j] = c ? atomicAdd(&cursor[j], c) : 0u;
    hist[j] = 0u;                        // reuse as local cursor
  }
  __syncthreads();
#pragma unroll
  for (int k = 0; k < 16; ++k) {
    unsigned b = km[k] >> 10;
    unsigned l = atomicAdd(&hist[b], 1u);
    unsigned pos = base[b] + l;
    if (pos < (b + 1u) * BCAP)           // overflow guard (unreachable at +8 sigma)
      tmp[(size_t)pos] = make_uint2(sm[k] | ((km[k] & 1023u) << 17), __float_as_uint(wm[k]));
  }
}

// ---------------- phase B: per-bucket counting sort over 1024 fine keys ----------------
// rp_fine stride 1025/bucket; entry 1024 = bucket end sentinel.
__global__ __launch_bounds__(256) void kbinB(const unsigned* __restrict__ cursor, const uint2* __restrict__ tmp,
                                             unsigned* __restrict__ rp_fine, uint2* __restrict__ edges) {
  __shared__ unsigned cnts[1024];
  __shared__ unsigned ps[256];
  int tid = threadIdx.x;
  unsigned b = blockIdx.x;
  unsigned s = b * BCAP;
  unsigned cnt = min(cursor[b], (b + 1u) * BCAP) - s;
  for (int j = tid; j < 1024; j += 256) cnts[j] = 0;
  __syncthreads();
  for (unsigned i = tid; i < cnt; i += 256) {
    unsigned lk = tmp[s + i].x >> 17;
    atomicAdd(&cnts[lk], 1u);
  }
  __syncthreads();
  unsigned c4[4], lsum = 0;
#pragma unroll
  for (int q = 0; q < 4; ++q) { c4[q] = cnts[tid * 4 + q]; lsum += c4[q]; }
  ps[tid] = lsum;
  __syncthreads();
  for (int o = 1; o < 256; o <<= 1) {
    unsigned v = (tid >= o) ? ps[tid - o] : 0u;
    __syncthreads();
    ps[tid] += v;
    __syncthreads();
  }
  unsigned excl = ps[tid] - lsum;
  __syncthreads();
#pragma unroll
  for (int q = 0; q < 4; ++q) {
    rp_fine[b * 1025u + (unsigned)tid * 4u + q] = s + excl;
    cnts[tid * 4 + q] = excl;            // lcur init
    excl += c4[q];
  }
  if (tid == 255) rp_fine[b * 1025u + 1024u] = s + cnt;
  __syncthreads();
  for (unsigned i = tid; i < cnt; i += 256) {
    uint2 r = tmp[s + i];
    unsigned lk = r.x >> 17;
    unsigned p = atomicAdd(&cnts[lk], 1u);
    edges[(size_t)s + p] = make_uint2(r.x & 0x1ffffu, r.y);
  }
}

// ---------------- FUSED: gather -> LDS(32KB) -> MFMA (B from L2) -> bias+LN -> out ----------------
// 512 threads, 32 dsts/block. sZ only LDS user -> 4 blocks/CU.
__global__ __launch_bounds__(512, 8) void kfuse(const uint2* __restrict__ edges, const unsigned* __restrict__ rp,
                                                const unsigned short* __restrict__ X,
                                                const unsigned short* __restrict__ Wimg, int layer,
                                                const float* __restrict__ bsum,
                                                const float* __restrict__ gw, const float* __restrict__ bw,
                                                unsigned short* __restrict__ outh, float* __restrict__ outf, int wf32) {
  __shared__ unsigned short sZ[32 * 512];   // 32KB
  const int tid = threadIdx.x;
  const int wv = tid >> 6;
  const int lane = tid & 63;
  const int g = lane >> 4;
  const int cl = lane & 15;
  const unsigned dbase = blockIdx.x * 32u;

  // ---- gather phase: each wave fills 4 rows of sZ ----
  const unsigned short* Xr = X + (size_t)(cl * 8);
  for (int it = 0; it < 4; ++it) {
    unsigned row = (unsigned)(wv * 4 + it);
    unsigned d = dbase + row;
    unsigned ridx = (d >> 8) * 1025u + ((d & 255u) << 2) + (unsigned)g;
    unsigned s = rp[ridx];
    unsigned e = rp[ridx + 1];
    unsigned len = e - s;
    int m = (int)len;
    m = max(m, __shfl_xor(m, 16, 64));
    m = max(m, __shfl_xor(m, 32, 64));
    __half2 accA[4], accB[4];
    const __half2 z2 = __half2(__half(0.f), __half(0.f));
#pragma unroll
    for (int k = 0; k < 4; ++k) { accA[k] = z2; accB[k] = z2; }
    unsigned jlast = len ? e - 1u : s;
    for (int i = 0; i < m; i += 4) {
      unsigned j[4], sidx[4];
      uint2 q[4];
      __half2 w2[4];
#pragma unroll
      for (int k = 0; k < 4; ++k) {
        bool v = (unsigned)(i + k) < len;
        j[k] = v ? s + (unsigned)(i + k) : jlast;
      }
#pragma unroll
      for (int k = 0; k < 4; ++k) q[k] = edges[j[k]];
#pragma unroll
      for (int k = 0; k < 4; ++k) {
        bool v = (unsigned)(i + k) < len;
        sidx[k] = v ? q[k].x : 0u;
        w2[k] = __float2half2_rn(v ? __uint_as_float(q[k].y) : 0.f);
      }
      uint4 u0 = *(const uint4*)(Xr + (size_t)sidx[0] * 128);
      uint4 u1 = *(const uint4*)(Xr + (size_t)sidx[1] * 128);
      uint4 u2 = *(const uint4*)(Xr + (size_t)sidx[2] * 128);
      uint4 u3 = *(const uint4*)(Xr + (size_t)sidx[3] * 128);
      accA[0] = __hfma2(w2[0], u2h2(u0.x), accA[0]);
      accA[1] = __hfma2(w2[0], u2h2(u0.y), accA[1]);
      accA[2] = __hfma2(w2[0], u2h2(u0.z), accA[2]);
      accA[3] = __hfma2(w2[0], u2h2(u0.w), accA[3]);
      accB[0] = __hfma2(w2[1], u2h2(u1.x), accB[0]);
      accB[1] = __hfma2(w2[1], u2h2(u1.y), accB[1]);
      accB[2] = __hfma2(w2[1], u2h2(u1.z), accB[2]);
      accB[3] = __hfma2(w2[1], u2h2(u1.w), accB[3]);
      accA[0] = __hfma2(w2[2], u2h2(u2.x), accA[0]);
      accA[1] = __hfma2(w2[2], u2h2(u2.y), accA[1]);
      accA[2] = __hfma2(w2[2], u2h2(u2.z), accA[2]);
      accA[3] = __hfma2(w2[2], u2h2(u2.w), accA[3]);
      accB[0] = __hfma2(w2[3], u2h2(u3.x), accB[0]);
      accB[1] = __hfma2(w2[3], u2h2(u3.y), accB[1]);
      accB[2] = __hfma2(w2[3], u2h2(u3.z), accB[2]);
      accB[3] = __hfma2(w2[3], u2h2(u3.w), accB[3]);
    }
    uint4 o;
    o.x = h22u(__hadd2(accA[0], accB[0]));
    o.y = h22u(__hadd2(accA[1], accB[1]));
    o.z = h22u(__hadd2(accA[2], accB[2]));
    o.w = h22u(__hadd2(accA[3], accB[3]));
    *(uint4*)((char*)sZ + row * 1024 + (((unsigned)(g * 256 + cl * 16)) ^ ((row & 7u) << 4))) = o;
  }
  __syncthreads();

  // ---- MFMA phase: [32x512] x [512x128]; wave=(mt,nh): 16 rows x 32 cols ----
  const int rlo = lane & 15;
  const int khi = lane >> 4;
  const int mt = wv >> 2;
  const int nh = wv & 3;
  f32x4 acc[2];
  acc[0] = (f32x4){0.f, 0.f, 0.f, 0.f};
  acc[1] = (f32x4){0.f, 0.f, 0.f, 0.f};
  const unsigned short* WL = Wimg + (size_t)layer * 65536;
  const int arow = mt * 16 + rlo;
  const unsigned abase = (unsigned)(arow * 1024);
  const unsigned aswz = (unsigned)((arow & 7) << 4);
#pragma unroll 4
  for (int kc = 0; kc < 16; ++kc) {
    f16x8 a = *(const f16x8*)((const char*)sZ + abase + (((unsigned)(kc * 64 + khi * 16)) ^ aswz));
    const f16x8* bp = (const f16x8*)(WL + (size_t)(((kc * 4 + khi) * 128) + nh * 32 + rlo) * 8);
    acc[0] = __builtin_amdgcn_mfma_f32_16x16x32_f16(a, bp[0], acc[0], 0, 0, 0);
    acc[1] = __builtin_amdgcn_mfma_f32_16x16x32_f16(a, bp[16], acc[1], 0, 0, 0);
  }

  // ---- epilogue: bias + LN; cross-wave column partials via LDS (reuse sZ) ----
  float bs[2], ggv[2], bwv[2];
#pragma unroll
  for (int n = 0; n < 2; ++n) {
    int cc = nh * 32 + n * 16 + rlo;
    bs[n] = bsum[cc];
    ggv[n] = gw[cc];
    bwv[n] = bw[cc];
  }
  __syncthreads();             // all MFMA reads of sZ done
  float* sPart = (float*)sZ;   // [32 rows][4 nh][2]
#pragma unroll
  for (int rg = 0; rg < 4; ++rg) {
    float v0 = acc[0][rg] + bs[0];
    float v1 = acc[1][rg] + bs[1];
    float s1 = v0 + v1;
    float s2 = v0 * v0 + v1 * v1;
    s1 += __shfl_xor(s1, 1, 64); s2 += __shfl_xor(s2, 1, 64);
    s1 += __shfl_xor(s1, 2, 64); s2 += __shfl_xor(s2, 2, 64);
    s1 += __shfl_xor(s1, 4, 64); s2 += __shfl_xor(s2, 4, 64);
    s1 += __shfl_xor(s1, 8, 64); s2 += __shfl_xor(s2, 8, 64);
    if (rlo == 0) {
      int row = mt * 16 + khi * 4 + rg;
      sPart[row * 8 + nh * 2] = s1;
      sPart[row * 8 + nh * 2 + 1] = s2;
    }
  }
  __syncthreads();
#pragma unroll
  for (int rg = 0; rg < 4; ++rg) {
    int row = mt * 16 + khi * 4 + rg;
    float s1 = sPart[row * 8 + 0] + sPart[row * 8 + 2] + sPart[row * 8 + 4] + sPart[row * 8 + 6];
    float s2 = sPart[row * 8 + 1] + sPart[row * 8 + 3] + sPart[row * 8 + 5] + sPart[row * 8 + 7];
    float mu = s1 * (1.f / 128.f);
    float var = fmaxf(s2 * (1.f / 128.f) - mu * mu, 0.f);
    float inv = rsqrtf(var + 1e-5f);
    size_t d = (size_t)dbase + (unsigned)row;
    if (wf32) {
#pragma unroll
      for (int n = 0; n < 2; ++n) {
        int cc = nh * 32 + n * 16 + rlo;
        outf[d * 128 + cc] = (acc[n][rg] + bs[n] - mu) * inv * ggv[n] + bwv[n];
      }
    } else {
#pragma unroll
      for (int n = 0; n < 2; ++n) {
        int cc = nh * 32 + n * 16 + rlo;
        outh[d * 128 + cc] = f2h((acc[n][rg] + bs[n] - mu) * inv * ggv[n] + bwv[n]);
      }
    }
  }
}

extern "C" void kernel_launch(void* const* d_in, const int* in_sizes, int n_in,
                              void* d_out, int out_size, void* d_ws, size_t ws_size,
                              hipStream_t stream) {
  (void)n_in; (void)out_size; (void)ws_size;
  const float* x = (const float*)d_in[0];
  const int* ei[4];
  const float *ew[4], *W1[4], *b1[4], *W2[4], *b2[4];
  const float *g1, *be1, *g2, *be2;
  if (in_sizes[2] == EE) {  // setup_inputs dict order
    for (int t = 0; t < 4; ++t) {
      int base = 1 + t * 6;
      ei[t] = (const int*)d_in[base + 0];
      ew[t] = (const float*)d_in[base + 1];
      W1[t] = (const float*)d_in[base + 2];
      b1[t] = (const float*)d_in[base + 3];
      W2[t] = (const float*)d_in[base + 4];
      b2[t] = (const float*)d_in[base + 5];
    }
  } else {  // reference() argument order
    for (int t = 0; t < 4; ++t) {
      ei[t] = (const int*)d_in[1 + t];
      ew[t] = (const float*)d_in[5 + t];
      W1[t] = (const float*)d_in[9 + t * 4 + 0];
      b1[t] = (const float*)d_in[9 + t * 4 + 1];
      W2[t] = (const float*)d_in[9 + t * 4 + 2];
      b2[t] = (const float*)d_in[9 + t * 4 + 3];
    }
  }
  g1 = (const float*)d_in[25];
  be1 = (const float*)d_in[26];
  g2 = (const float*)d_in[27];
  be2 = (const float*)d_in[28];

  char* ws = (char*)d_ws;
  size_t off = 0;
  auto take = [&](size_t b) { char* p = ws + off; off = (off + b + 255) & ~(size_t)255; return p; };
  unsigned* cursor  = (unsigned*)take(512 * 4);
  unsigned* rp_fine = (unsigned*)take(512ull * 1025 * 4);
  unsigned short* Wimg3 = (unsigned short*)take(2ull * 65536 * 2);
  float* bsum       = (float*)take(256 * 4);
  uint2* edges      = (uint2*)take(512ull * BCAP * 8);
  unsigned short* Xh = (unsigned short*)take((size_t)NN * 128 * 2);
  unsigned short* Yh = (unsigned short*)take((size_t)NN * 128 * 2);
  uint2* tmp = (uint2*)d_out;  // 18.9 MB scratch; dead before any d_out output write

  kprep<<<16899, 256, 0, stream>>>((const float4*)x, (ushort4*)Xh,
                                   W1[0], W1[1], W1[2], W1[3], W2[0], W2[1], W2[2], W2[3], Wimg3,
                                   cursor,
                                   b1[0], b1[1], b1[2], b1[3], b2[0], b2[1], b2[2], b2[3], bsum);
  kbinA<<<512, 256, 0, stream>>>(ei[0], ei[1], ei[2], ei[3], ew[0], ew[1], ew[2], ew[3], cursor, tmp);
  kbinB<<<512, 256, 0, stream>>>(cursor, tmp, rp_fine, edges);

  // layer 1: fused gather+GEMM+LN -> Yh (fp16, workspace)
  kfuse<<<NN / 32, 512, 0, stream>>>(edges, rp_fine, Xh, Wimg3, 0, bsum, g1, be1, Yh, nullptr, 0);
  // layer 2: fused gather+GEMM+LN -> d_out (fp32)
  kfuse<<<NN / 32, 512, 0, stream>>>(edges, rp_fine, Yh, Wimg3, 1, bsum + 128, g2, be2, nullptr, (float*)d_out, 1);
}